// Round 1
// baseline (5824.711 us; speedup 1.0000x reference)
//
#include <hip/hip_runtime.h>

#define DD 80
#define CIN 32
#define PLANE (DD*DD)        // 6400
#define VOX (DD*DD*DD)       // 512000
#define NPTS 200000

// ---------------- K0: permute w_enc2 (64,64,3,3,3) -> wp[oc][off*64+ic] ----------------
__global__ void permute_w2(const float* __restrict__ w2, float* __restrict__ wp) {
    int i = blockIdx.x * 256 + threadIdx.x;      // 64*1728 = 110592
    if (i >= 64 * 1728) return;
    int oc = i / 1728, j = i - oc * 1728;
    int off = j >> 6, ic = j & 63;
    wp[i] = w2[oc * 1728 + ic * 27 + off];
}

// ---------------- K1: conv1 + relu, img (32,80,80,80) -> f1 [vox][64] ----------------
__global__ __launch_bounds__(256) void conv1_kernel(
    const float* __restrict__ img, const float* __restrict__ w1,
    const float* __restrict__ b1, float* __restrict__ f1)
{
    const int bh = blockIdx.x;           // 0..6399
    const int d = bh / DD, h = bh - d * DD;
    const int tid = threadIdx.x;
    const int oc = tid & 63, grp = tid >> 6;
    const int wb = grp * 20;

    __shared__ float rows[9 * 82];

    float acc[20];
    #pragma unroll
    for (int i = 0; i < 20; i++) acc[i] = 0.f;

    for (int ic = 0; ic < CIN; ++ic) {
        // stage 9 rows (3 kd x 3 kh) of width 82 (zero-padded ends)
        for (int i = tid; i < 9 * 82; i += 256) {
            int r = i / 82, c = i - r * 82;
            int kd = r / 3, kh = r - kd * 3;
            int zd = d + kd - 1, zh = h + kh - 1, zw = c - 1;
            float v = 0.f;
            if ((unsigned)zd < DD && (unsigned)zh < DD && (unsigned)zw < DD)
                v = img[ic * VOX + zd * PLANE + zh * DD + zw];
            rows[i] = v;
        }
        __syncthreads();

        float wk[27];
        const float* wptr = w1 + (oc * CIN + ic) * 27;
        #pragma unroll
        for (int i = 0; i < 27; i++) wk[i] = wptr[i];

        #pragma unroll
        for (int r = 0; r < 9; r++) {
            float rv[22];
            #pragma unroll
            for (int i = 0; i < 22; i++) rv[i] = rows[r * 82 + wb + i];
            #pragma unroll
            for (int v = 0; v < 20; v++)
                acc[v] += wk[r * 3 + 0] * rv[v] + wk[r * 3 + 1] * rv[v + 1] + wk[r * 3 + 2] * rv[v + 2];
        }
        __syncthreads();   // protect rows before next ic overwrites
    }

    float bias = b1[oc];
    const int vbase = d * PLANE + h * DD + wb;
    #pragma unroll
    for (int v = 0; v < 20; v++) {
        float x = acc[v] + bias;
        f1[(vbase + v) * 64 + oc] = x > 0.f ? x : 0.f;
    }
}

// ---------------- K2: conv2 at gathered points + relu -> g [pt][64] ----------------
// block = 8 points; nb[p][q] q = off*16 + ic4 (float4 over channels)
__global__ __launch_bounds__(256) void conv2_gather(
    const float* __restrict__ f1, const float* __restrict__ wp,
    const float* __restrict__ b2,
    const int* __restrict__ c0, const int* __restrict__ c1, const int* __restrict__ c2,
    float* __restrict__ g)
{
    __shared__ float4 nb[8][432];
    __shared__ float red[2048];
    const int tid = threadIdx.x;
    const int pbase = blockIdx.x * 8;

    for (int i4 = tid; i4 < 8 * 432; i4 += 256) {
        int p = i4 / 432, q = i4 - p * 432;
        int off = q >> 4, icq = q & 15;
        int dz = off / 9, rem = off - dz * 9;
        int dy = rem / 3, dx = rem - dy * 3;
        int z = c0[pbase + p] + dz - 1;
        int y = c1[pbase + p] + dy - 1;
        int x = c2[pbase + p] + dx - 1;
        float4 v = make_float4(0.f, 0.f, 0.f, 0.f);
        if ((unsigned)z < DD && (unsigned)y < DD && (unsigned)x < DD)
            v = *(const float4*)(f1 + (z * PLANE + y * DD + x) * 64 + icq * 4);
        nb[p][q] = v;
    }
    __syncthreads();

    const int og = tid & 15, part = tid >> 4;
    const int ocb = og * 4;
    float acc[4][8];
    #pragma unroll
    for (int o = 0; o < 4; o++)
        #pragma unroll
        for (int p = 0; p < 8; p++) acc[o][p] = 0.f;

    const int qb = part * 27;
    const float4* wp4 = (const float4*)wp;
    for (int c = 0; c < 27; ++c) {
        int q = qb + c;
        float4 w0 = wp4[(ocb + 0) * 432 + q];
        float4 w1 = wp4[(ocb + 1) * 432 + q];
        float4 w2 = wp4[(ocb + 2) * 432 + q];
        float4 w3 = wp4[(ocb + 3) * 432 + q];
        #pragma unroll
        for (int p = 0; p < 8; p++) {
            float4 nv = nb[p][q];
            acc[0][p] += w0.x * nv.x + w0.y * nv.y + w0.z * nv.z + w0.w * nv.w;
            acc[1][p] += w1.x * nv.x + w1.y * nv.y + w1.z * nv.z + w1.w * nv.w;
            acc[2][p] += w2.x * nv.x + w2.y * nv.y + w2.z * nv.z + w2.w * nv.w;
            acc[3][p] += w3.x * nv.x + w3.y * nv.y + w3.z * nv.z + w3.w * nv.w;
        }
    }

    const int lane = tid & 63, wave = tid >> 6;
    #pragma unroll
    for (int o = 0; o < 4; o++) {
        #pragma unroll
        for (int p = 0; p < 8; p++) {
            float v = acc[o][p];
            v += __shfl_down(v, 32, 64);
            v += __shfl_down(v, 16, 64);
            if (lane < 16) red[wave * 512 + og * 32 + o * 8 + p] = v;
        }
    }
    __syncthreads();

    for (int e = tid; e < 512; e += 256) {
        int oc = e >> 3, p = e & 7;
        int idx = (oc >> 2) * 32 + (oc & 3) * 8 + p;
        float s = b2[oc] + red[idx] + red[512 + idx] + red[1024 + idx] + red[1536 + idx];
        g[(pbase + p) * 64 + oc] = s > 0.f ? s : 0.f;
    }
}

// ---------------- K3: fused MLP 64->256->256->64->6, block = 16 points ----------------
__global__ __launch_bounds__(256) void mlp_kernel(
    const float* __restrict__ g,
    const float* __restrict__ wp1, const float* __restrict__ bp1,
    const float* __restrict__ wp2, const float* __restrict__ bp2,
    const float* __restrict__ wp3, const float* __restrict__ bp3,
    const float* __restrict__ wp4, const float* __restrict__ bp4,
    float* __restrict__ out)
{
    __shared__ float gl[16 * 64];     // reused as h3 after L2
    __shared__ float h1[16 * 256];
    __shared__ float h2[16 * 256];
    const int tid = threadIdx.x;
    const int pb = blockIdx.x * 16;

    // load g tile (1024 floats = 256 float4)
    ((float4*)gl)[tid] = ((const float4*)(g + pb * 64))[tid];
    __syncthreads();

    // L1: 64 -> 256, relu. thread: 2 channels x 8 points
    {
        const int cb = (tid & 127) * 2, ph = tid >> 7;
        const int p0 = ph * 8;
        float a0[8], a1[8];
        #pragma unroll
        for (int p = 0; p < 8; p++) { a0[p] = 0.f; a1[p] = 0.f; }
        const float4* w0r = (const float4*)(wp1 + (cb + 0) * 64);
        const float4* w1r = (const float4*)(wp1 + (cb + 1) * 64);
        for (int k4 = 0; k4 < 16; ++k4) {
            float4 w0 = w0r[k4], w1 = w1r[k4];
            #pragma unroll
            for (int p = 0; p < 8; p++) {
                float4 x = ((const float4*)(gl + (p0 + p) * 64))[k4];
                a0[p] += w0.x * x.x + w0.y * x.y + w0.z * x.z + w0.w * x.w;
                a1[p] += w1.x * x.x + w1.y * x.y + w1.z * x.z + w1.w * x.w;
            }
        }
        float bb0 = bp1[cb], bb1 = bp1[cb + 1];
        #pragma unroll
        for (int p = 0; p < 8; p++) {
            float v0 = a0[p] + bb0, v1 = a1[p] + bb1;
            h1[(p0 + p) * 256 + cb]     = v0 > 0.f ? v0 : 0.f;
            h1[(p0 + p) * 256 + cb + 1] = v1 > 0.f ? v1 : 0.f;
        }
    }
    __syncthreads();

    // L2: 256 -> 256, relu
    {
        const int cb = (tid & 127) * 2, ph = tid >> 7;
        const int p0 = ph * 8;
        float a0[8], a1[8];
        #pragma unroll
        for (int p = 0; p < 8; p++) { a0[p] = 0.f; a1[p] = 0.f; }
        const float4* w0r = (const float4*)(wp2 + (cb + 0) * 256);
        const float4* w1r = (const float4*)(wp2 + (cb + 1) * 256);
        for (int k4 = 0; k4 < 64; ++k4) {
            float4 w0 = w0r[k4], w1 = w1r[k4];
            #pragma unroll
            for (int p = 0; p < 8; p++) {
                float4 x = ((const float4*)(h1 + (p0 + p) * 256))[k4];
                a0[p] += w0.x * x.x + w0.y * x.y + w0.z * x.z + w0.w * x.w;
                a1[p] += w1.x * x.x + w1.y * x.y + w1.z * x.z + w1.w * x.w;
            }
        }
        float bb0 = bp2[cb], bb1 = bp2[cb + 1];
        #pragma unroll
        for (int p = 0; p < 8; p++) {
            float v0 = a0[p] + bb0, v1 = a1[p] + bb1;
            h2[(p0 + p) * 256 + cb]     = v0 > 0.f ? v0 : 0.f;
            h2[(p0 + p) * 256 + cb + 1] = v1 > 0.f ? v1 : 0.f;
        }
    }
    __syncthreads();

    // L3: 256 -> 64, no relu. thread: 1 channel x 4 points. h3 goes into gl.
    {
        const int c = tid & 63, p0 = (tid >> 6) * 4;
        float a[4];
        #pragma unroll
        for (int p = 0; p < 4; p++) a[p] = 0.f;
        const float4* wr = (const float4*)(wp3 + c * 256);
        for (int k4 = 0; k4 < 64; ++k4) {
            float4 w = wr[k4];
            #pragma unroll
            for (int p = 0; p < 4; p++) {
                float4 x = ((const float4*)(h2 + (p0 + p) * 256))[k4];
                a[p] += w.x * x.x + w.y * x.y + w.z * x.z + w.w * x.w;
            }
        }
        float bb = bp3[c];
        #pragma unroll
        for (int p = 0; p < 4; p++)
            gl[(p0 + p) * 64 + c] = a[p] + bb;
    }
    __syncthreads();

    // L4: 64 -> 6. 96 outputs, one per thread.
    if (tid < 96) {
        const int c = tid >> 4, p = tid & 15;
        float a = bp4[c];
        const float4* wr = (const float4*)(wp4 + c * 64);
        const float4* xr = (const float4*)(gl + p * 64);
        for (int k4 = 0; k4 < 16; ++k4) {
            float4 w = wr[k4], x = xr[k4];
            a += w.x * x.x + w.y * x.y + w.z * x.z + w.w * x.w;
        }
        out[c * NPTS + pb + p] = a;
    }
}

extern "C" void kernel_launch(void* const* d_in, const int* in_sizes, int n_in,
                              void* d_out, int out_size, void* d_ws, size_t ws_size,
                              hipStream_t stream) {
    const float* img = (const float*)d_in[0];
    const int* c0 = (const int*)d_in[1];
    const int* c1 = (const int*)d_in[2];
    const int* c2 = (const int*)d_in[3];
    const float* w_enc1 = (const float*)d_in[4];
    const float* b_enc1 = (const float*)d_in[5];
    const float* w_enc2 = (const float*)d_in[6];
    const float* b_enc2 = (const float*)d_in[7];
    const float* w_p1 = (const float*)d_in[8];
    const float* b_p1 = (const float*)d_in[9];
    const float* w_p2 = (const float*)d_in[10];
    const float* b_p2 = (const float*)d_in[11];
    const float* w_p3 = (const float*)d_in[12];
    const float* b_p3 = (const float*)d_in[13];
    const float* w_p4 = (const float*)d_in[14];
    const float* b_p4 = (const float*)d_in[15];
    float* out = (float*)d_out;

    float* f1 = (float*)d_ws;                  // 32,768,000 floats (131 MB)
    float* wp = f1 + (size_t)VOX * 64;         // 110,592 floats
    float* g  = wp + 64 * 1728;                // 12,800,000 floats (51.2 MB)

    permute_w2<<<(64 * 1728 + 255) / 256, 256, 0, stream>>>(w_enc2, wp);
    conv1_kernel<<<DD * DD, 256, 0, stream>>>(img, w_enc1, b_enc1, f1);
    conv2_gather<<<NPTS / 8, 256, 0, stream>>>(f1, wp, b_enc2, c0, c1, c2, g);
    mlp_kernel<<<NPTS / 16, 256, 0, stream>>>(g, w_p1, b_p1, w_p2, b_p2,
                                              w_p3, b_p3, w_p4, b_p4, out);
}

// Round 2
// 3257.451 us; speedup vs baseline: 1.7881x; 1.7881x over previous
//
#include <hip/hip_runtime.h>
#include <hip/hip_bf16.h>

#define DD 80
#define CIN 32
#define PLANE (DD*DD)        // 6400
#define VOX (DD*DD*DD)       // 512000
#define NPTS 200000

typedef __attribute__((ext_vector_type(8))) short bf16x8;
typedef __attribute__((ext_vector_type(4))) float floatx4;

// ---------------- K0: permute w_enc2 (64,64,3,3,3) -> wpb[oc][off*64+ic] (bf16) ----------------
__global__ void permute_w2(const float* __restrict__ w2, __hip_bfloat16* __restrict__ wp) {
    int i = blockIdx.x * 256 + threadIdx.x;      // 64*1728 = 110592
    if (i >= 64 * 1728) return;
    int oc = i / 1728, j = i - oc * 1728;
    int off = j >> 6, ic = j & 63;
    wp[i] = __float2bfloat16(w2[oc * 1728 + ic * 27 + off]);
}

// ---------------- K1: conv1 + relu, img (32,80,80,80) -> f1 [vox][64] bf16 ----------------
__global__ __launch_bounds__(256) void conv1_kernel(
    const float* __restrict__ img, const float* __restrict__ w1,
    const float* __restrict__ b1, __hip_bfloat16* __restrict__ f1)
{
    const int bh = blockIdx.x;           // 0..6399
    const int d = bh / DD, h = bh - d * DD;
    const int tid = threadIdx.x;
    const int oc = tid & 63, grp = tid >> 6;
    const int wb = grp * 20;

    __shared__ float rows[9 * 82];

    float acc[20];
    #pragma unroll
    for (int i = 0; i < 20; i++) acc[i] = 0.f;

    for (int ic = 0; ic < CIN; ++ic) {
        for (int i = tid; i < 9 * 82; i += 256) {
            int r = i / 82, c = i - r * 82;
            int kd = r / 3, kh = r - kd * 3;
            int zd = d + kd - 1, zh = h + kh - 1, zw = c - 1;
            float v = 0.f;
            if ((unsigned)zd < DD && (unsigned)zh < DD && (unsigned)zw < DD)
                v = img[ic * VOX + zd * PLANE + zh * DD + zw];
            rows[i] = v;
        }
        __syncthreads();

        float wk[27];
        const float* wptr = w1 + (oc * CIN + ic) * 27;
        #pragma unroll
        for (int i = 0; i < 27; i++) wk[i] = wptr[i];

        #pragma unroll
        for (int r = 0; r < 9; r++) {
            float rv[22];
            #pragma unroll
            for (int i = 0; i < 22; i++) rv[i] = rows[r * 82 + wb + i];
            #pragma unroll
            for (int v = 0; v < 20; v++)
                acc[v] += wk[r * 3 + 0] * rv[v] + wk[r * 3 + 1] * rv[v + 1] + wk[r * 3 + 2] * rv[v + 2];
        }
        __syncthreads();
    }

    float bias = b1[oc];
    const int vbase = d * PLANE + h * DD + wb;
    #pragma unroll
    for (int v = 0; v < 20; v++) {
        float x = acc[v] + bias;
        f1[(size_t)(vbase + v) * 64 + oc] = __float2bfloat16(x > 0.f ? x : 0.f);
    }
}

// ---------------- K2: conv2 at gathered points via bf16 MFMA -> g [pt][64] fp32 ----------------
// GEMM: C[256 pts][64 oc] += A[pt][64 ic] * W[ic][oc] per 3^3 offset.
// A staged in LDS (stride 72 to avoid bank conflicts), W chunk staged in LDS.
__global__ __launch_bounds__(256) void conv2_mfma(
    const __hip_bfloat16* __restrict__ f1b, const __hip_bfloat16* __restrict__ wpb,
    const float* __restrict__ b2,
    const int* __restrict__ c0, const int* __restrict__ c1, const int* __restrict__ c2,
    float* __restrict__ g)
{
    __shared__ short Alds[256 * 72];   // 36 KB, padded stride 72 (144 B = 36 banks)
    __shared__ short Blds[64 * 72];    // 9 KB

    const int tid = threadIdx.x;
    const int pbase = blockIdx.x * 256;
    const int w = tid >> 6, lane = tid & 63;
    const int quad = lane >> 4, lc = lane & 15;

    // each thread stages 8 A-rows (fixed across offsets): rows r0+32*i, 16B chunk `chunk`
    const int r0 = tid >> 3, chunk = tid & 7;
    int rowbase[8];
    int rowmask[8];
    #pragma unroll
    for (int i = 0; i < 8; i++) {
        int r = r0 + 32 * i;
        int p = pbase + r; if (p > NPTS - 1) p = NPTS - 1;
        int z = c0[p], y = c1[p], x = c2[p];
        rowbase[i] = (z * PLANE + y * DD + x) * 64;
        int m = 0;
        #pragma unroll
        for (int off = 0; off < 27; off++) {
            int dz = off / 9, dy = (off / 3) % 3, dx = off % 3;
            int ok = ((unsigned)(z + dz - 1) < DD) & ((unsigned)(y + dy - 1) < DD) &
                     ((unsigned)(x + dx - 1) < DD);
            m |= ok << off;
        }
        rowmask[i] = m;
    }

    floatx4 acc[4][4];
    #pragma unroll
    for (int rt = 0; rt < 4; rt++)
        #pragma unroll
        for (int nt = 0; nt < 4; nt++)
            acc[rt][nt] = (floatx4){0.f, 0.f, 0.f, 0.f};

    const short* f1s = (const short*)f1b;
    const short* wps = (const short*)wpb;

    for (int off = 0; off < 27; ++off) {
        const int dz = off / 9, dy = (off / 3) % 3, dx = off % 3;
        const int delta = ((dz - 1) * PLANE + (dy - 1) * DD + (dx - 1)) * 64;

        __syncthreads();   // previous tile fully consumed

        // stage A: 256 rows x 128 B
        #pragma unroll
        for (int i = 0; i < 8; i++) {
            int4 v = make_int4(0, 0, 0, 0);
            if ((rowmask[i] >> off) & 1)
                v = *(const int4*)(f1s + rowbase[i] + delta + chunk * 8);
            *(int4*)(&Alds[(r0 + 32 * i) * 72 + chunk * 8]) = v;
        }
        // stage B: 64 oc x 128 B for this offset
        #pragma unroll
        for (int it = 0; it < 2; it++) {
            int idx = it * 256 + tid;
            int oc = idx >> 3, ch = idx & 7;
            int4 v = *(const int4*)(wps + oc * 1728 + off * 64 + ch * 8);
            *(int4*)(&Blds[oc * 72 + ch * 8]) = v;
        }
        __syncthreads();

        // compute: K=64 in two k-steps of 32
        #pragma unroll
        for (int ks = 0; ks < 2; ks++) {
            const int kl = ks * 32 + quad * 8;
            bf16x8 bfr[4];
            #pragma unroll
            for (int nt = 0; nt < 4; nt++)
                bfr[nt] = *(const bf16x8*)(&Blds[(nt * 16 + lc) * 72 + kl]);
            #pragma unroll
            for (int rt = 0; rt < 4; rt++) {
                bf16x8 afr = *(const bf16x8*)(&Alds[(w * 64 + rt * 16 + lc) * 72 + kl]);
                #pragma unroll
                for (int nt = 0; nt < 4; nt++)
                    acc[rt][nt] = __builtin_amdgcn_mfma_f32_16x16x32_bf16(
                        afr, bfr[nt], acc[rt][nt], 0, 0, 0);
            }
        }
    }

    // epilogue: bias + relu, C[row=quad*4+r][col=lc] per tile
    #pragma unroll
    for (int nt = 0; nt < 4; nt++) {
        const int oc = nt * 16 + lc;
        const float bias = b2[oc];
        #pragma unroll
        for (int rt = 0; rt < 4; rt++) {
            const int pt = pbase + w * 64 + rt * 16 + quad * 4;
            #pragma unroll
            for (int r = 0; r < 4; r++) {
                if (pt + r < NPTS) {
                    float v = acc[rt][nt][r] + bias;
                    g[(size_t)(pt + r) * 64 + oc] = v > 0.f ? v : 0.f;
                }
            }
        }
    }
}

// ---------------- K3: fused MLP 64->256->256->64->6, block = 16 points ----------------
__global__ __launch_bounds__(256) void mlp_kernel(
    const float* __restrict__ g,
    const float* __restrict__ wp1, const float* __restrict__ bp1,
    const float* __restrict__ wp2, const float* __restrict__ bp2,
    const float* __restrict__ wp3, const float* __restrict__ bp3,
    const float* __restrict__ wp4, const float* __restrict__ bp4,
    float* __restrict__ out)
{
    __shared__ float gl[16 * 64];     // reused as h3 after L2
    __shared__ float h1[16 * 256];
    __shared__ float h2[16 * 256];
    const int tid = threadIdx.x;
    const int pb = blockIdx.x * 16;

    ((float4*)gl)[tid] = ((const float4*)(g + (size_t)pb * 64))[tid];
    __syncthreads();

    // L1: 64 -> 256, relu
    {
        const int cb = (tid & 127) * 2, ph = tid >> 7;
        const int p0 = ph * 8;
        float a0[8], a1[8];
        #pragma unroll
        for (int p = 0; p < 8; p++) { a0[p] = 0.f; a1[p] = 0.f; }
        const float4* w0r = (const float4*)(wp1 + (cb + 0) * 64);
        const float4* w1r = (const float4*)(wp1 + (cb + 1) * 64);
        for (int k4 = 0; k4 < 16; ++k4) {
            float4 w0 = w0r[k4], w1 = w1r[k4];
            #pragma unroll
            for (int p = 0; p < 8; p++) {
                float4 x = ((const float4*)(gl + (p0 + p) * 64))[k4];
                a0[p] += w0.x * x.x + w0.y * x.y + w0.z * x.z + w0.w * x.w;
                a1[p] += w1.x * x.x + w1.y * x.y + w1.z * x.z + w1.w * x.w;
            }
        }
        float bb0 = bp1[cb], bb1 = bp1[cb + 1];
        #pragma unroll
        for (int p = 0; p < 8; p++) {
            float v0 = a0[p] + bb0, v1 = a1[p] + bb1;
            h1[(p0 + p) * 256 + cb]     = v0 > 0.f ? v0 : 0.f;
            h1[(p0 + p) * 256 + cb + 1] = v1 > 0.f ? v1 : 0.f;
        }
    }
    __syncthreads();

    // L2: 256 -> 256, relu
    {
        const int cb = (tid & 127) * 2, ph = tid >> 7;
        const int p0 = ph * 8;
        float a0[8], a1[8];
        #pragma unroll
        for (int p = 0; p < 8; p++) { a0[p] = 0.f; a1[p] = 0.f; }
        const float4* w0r = (const float4*)(wp2 + (cb + 0) * 256);
        const float4* w1r = (const float4*)(wp2 + (cb + 1) * 256);
        for (int k4 = 0; k4 < 64; ++k4) {
            float4 w0 = w0r[k4], w1 = w1r[k4];
            #pragma unroll
            for (int p = 0; p < 8; p++) {
                float4 x = ((const float4*)(h1 + (p0 + p) * 256))[k4];
                a0[p] += w0.x * x.x + w0.y * x.y + w0.z * x.z + w0.w * x.w;
                a1[p] += w1.x * x.x + w1.y * x.y + w1.z * x.z + w1.w * x.w;
            }
        }
        float bb0 = bp2[cb], bb1 = bp2[cb + 1];
        #pragma unroll
        for (int p = 0; p < 8; p++) {
            float v0 = a0[p] + bb0, v1 = a1[p] + bb1;
            h2[(p0 + p) * 256 + cb]     = v0 > 0.f ? v0 : 0.f;
            h2[(p0 + p) * 256 + cb + 1] = v1 > 0.f ? v1 : 0.f;
        }
    }
    __syncthreads();

    // L3: 256 -> 64, no relu
    {
        const int c = tid & 63, p0 = (tid >> 6) * 4;
        float a[4];
        #pragma unroll
        for (int p = 0; p < 4; p++) a[p] = 0.f;
        const float4* wr = (const float4*)(wp3 + c * 256);
        for (int k4 = 0; k4 < 64; ++k4) {
            float4 w = wr[k4];
            #pragma unroll
            for (int p = 0; p < 4; p++) {
                float4 x = ((const float4*)(h2 + (p0 + p) * 256))[k4];
                a[p] += w.x * x.x + w.y * x.y + w.z * x.z + w.w * x.w;
            }
        }
        float bb = bp3[c];
        #pragma unroll
        for (int p = 0; p < 4; p++)
            gl[(p0 + p) * 64 + c] = a[p] + bb;
    }
    __syncthreads();

    // L4: 64 -> 6
    if (tid < 96) {
        const int c = tid >> 4, p = tid & 15;
        float a = bp4[c];
        const float4* wr = (const float4*)(wp4 + c * 64);
        const float4* xr = (const float4*)(gl + p * 64);
        for (int k4 = 0; k4 < 16; ++k4) {
            float4 w = wr[k4], x = xr[k4];
            a += w.x * x.x + w.y * x.y + w.z * x.z + w.w * x.w;
        }
        out[c * NPTS + pb + p] = a;
    }
}

extern "C" void kernel_launch(void* const* d_in, const int* in_sizes, int n_in,
                              void* d_out, int out_size, void* d_ws, size_t ws_size,
                              hipStream_t stream) {
    const float* img = (const float*)d_in[0];
    const int* c0 = (const int*)d_in[1];
    const int* c1 = (const int*)d_in[2];
    const int* c2 = (const int*)d_in[3];
    const float* w_enc1 = (const float*)d_in[4];
    const float* b_enc1 = (const float*)d_in[5];
    const float* w_enc2 = (const float*)d_in[6];
    const float* b_enc2 = (const float*)d_in[7];
    const float* w_p1 = (const float*)d_in[8];
    const float* b_p1 = (const float*)d_in[9];
    const float* w_p2 = (const float*)d_in[10];
    const float* b_p2 = (const float*)d_in[11];
    const float* w_p3 = (const float*)d_in[12];
    const float* b_p3 = (const float*)d_in[13];
    const float* w_p4 = (const float*)d_in[14];
    const float* b_p4 = (const float*)d_in[15];
    float* out = (float*)d_out;

    __hip_bfloat16* f1b = (__hip_bfloat16*)d_ws;            // 512000*64 bf16 = 65.5 MB
    __hip_bfloat16* wpb = f1b + (size_t)VOX * 64;           // 110592 bf16
    float* g = (float*)(wpb + 64 * 1728);                   // 200000*64 fp32 = 51.2 MB

    permute_w2<<<(64 * 1728 + 255) / 256, 256, 0, stream>>>(w_enc2, wpb);
    conv1_kernel<<<DD * DD, 256, 0, stream>>>(img, w_enc1, b_enc1, f1b);
    conv2_mfma<<<(NPTS + 255) / 256, 256, 0, stream>>>(f1b, wpb, b_enc2, c0, c1, c2, g);
    mlp_kernel<<<NPTS / 16, 256, 0, stream>>>(g, w_p1, b_p1, w_p2, b_p2,
                                              w_p3, b_p3, w_p4, b_p4, out);
}

// Round 3
// 1712.500 us; speedup vs baseline: 3.4013x; 1.9022x over previous
//
#include <hip/hip_runtime.h>
#include <hip/hip_bf16.h>

#define DD 80
#define CIN 32
#define PLANE (DD*DD)        // 6400
#define VOX (DD*DD*DD)       // 512000
#define NPTS 200000

typedef __attribute__((ext_vector_type(8))) short bf16x8;
typedef __attribute__((ext_vector_type(4))) float floatx4;

static __device__ __forceinline__ short f2bf(float v) {
    __hip_bfloat16 b = __float2bfloat16(v);
    return *(short*)&b;
}

// ---------------- K0: convert/permute all weights to bf16 ----------------
// wpb[oc][off*64+ic] from w_enc2(64,64,3,3,3); w1b/w2b/w3b row-major [n][k] bf16
__global__ void convert_weights(const float* __restrict__ w2,
                                const float* __restrict__ w_p1,
                                const float* __restrict__ w_p2,
                                const float* __restrict__ w_p3,
                                short* __restrict__ wpb, short* __restrict__ w1b,
                                short* __restrict__ w2b, short* __restrict__ w3b) {
    int i = blockIdx.x * 256 + threadIdx.x;      // total 208896
    if (i < 110592) {
        int oc = i / 1728, j = i - oc * 1728;
        int off = j >> 6, ic = j & 63;
        wpb[i] = f2bf(w2[oc * 1728 + ic * 27 + off]);
    } else if (i < 110592 + 16384) {
        int j = i - 110592;
        w1b[j] = f2bf(w_p1[j]);
    } else if (i < 110592 + 16384 + 65536) {
        int j = i - 110592 - 16384;
        w2b[j] = f2bf(w_p2[j]);
    } else if (i < 110592 + 16384 + 65536 + 16384) {
        int j = i - 110592 - 16384 - 65536;
        w3b[j] = f2bf(w_p3[j]);
    }
}

// ---------------- K1: conv1 + relu, img (32,80,80,80) -> f1 [vox][64] bf16 ----------------
__global__ __launch_bounds__(256) void conv1_kernel(
    const float* __restrict__ img, const float* __restrict__ w1,
    const float* __restrict__ b1, __hip_bfloat16* __restrict__ f1)
{
    const int bh = blockIdx.x;           // 0..6399
    const int d = bh / DD, h = bh - d * DD;
    const int tid = threadIdx.x;
    const int oc = tid & 63, grp = tid >> 6;
    const int wb = grp * 20;

    __shared__ float rows[9 * 82];

    float acc[20];
    #pragma unroll
    for (int i = 0; i < 20; i++) acc[i] = 0.f;

    for (int ic = 0; ic < CIN; ++ic) {
        for (int i = tid; i < 9 * 82; i += 256) {
            int r = i / 82, c = i - r * 82;
            int kd = r / 3, kh = r - kd * 3;
            int zd = d + kd - 1, zh = h + kh - 1, zw = c - 1;
            float v = 0.f;
            if ((unsigned)zd < DD && (unsigned)zh < DD && (unsigned)zw < DD)
                v = img[ic * VOX + zd * PLANE + zh * DD + zw];
            rows[i] = v;
        }
        __syncthreads();

        float wk[27];
        const float* wptr = w1 + (oc * CIN + ic) * 27;
        #pragma unroll
        for (int i = 0; i < 27; i++) wk[i] = wptr[i];

        #pragma unroll
        for (int r = 0; r < 9; r++) {
            float rv[22];
            #pragma unroll
            for (int i = 0; i < 22; i++) rv[i] = rows[r * 82 + wb + i];
            #pragma unroll
            for (int v = 0; v < 20; v++)
                acc[v] += wk[r * 3 + 0] * rv[v] + wk[r * 3 + 1] * rv[v + 1] + wk[r * 3 + 2] * rv[v + 2];
        }
        __syncthreads();
    }

    float bias = b1[oc];
    const int vbase = d * PLANE + h * DD + wb;
    #pragma unroll
    for (int v = 0; v < 20; v++) {
        float x = acc[v] + bias;
        f1[(size_t)(vbase + v) * 64 + oc] = __float2bfloat16(x > 0.f ? x : 0.f);
    }
}

// ---------------- K2: conv2 at gathered points via bf16 MFMA -> g [pt][64] bf16 ----------------
__global__ __launch_bounds__(256) void conv2_mfma(
    const __hip_bfloat16* __restrict__ f1b, const short* __restrict__ wpb,
    const float* __restrict__ b2,
    const int* __restrict__ c0, const int* __restrict__ c1, const int* __restrict__ c2,
    __hip_bfloat16* __restrict__ g)
{
    __shared__ short Alds[256 * 72];   // 36 KB, padded stride 72
    __shared__ short Blds[64 * 72];    // 9 KB

    const int tid = threadIdx.x;
    const int pbase = blockIdx.x * 256;
    const int w = tid >> 6, lane = tid & 63;
    const int quad = lane >> 4, lc = lane & 15;

    const int r0 = tid >> 3, chunk = tid & 7;
    int rowbase[8];
    int rowmask[8];
    #pragma unroll
    for (int i = 0; i < 8; i++) {
        int r = r0 + 32 * i;
        int p = pbase + r; if (p > NPTS - 1) p = NPTS - 1;
        int z = c0[p], y = c1[p], x = c2[p];
        rowbase[i] = (z * PLANE + y * DD + x) * 64;
        int m = 0;
        #pragma unroll
        for (int off = 0; off < 27; off++) {
            int dz = off / 9, dy = (off / 3) % 3, dx = off % 3;
            int ok = ((unsigned)(z + dz - 1) < DD) & ((unsigned)(y + dy - 1) < DD) &
                     ((unsigned)(x + dx - 1) < DD);
            m |= ok << off;
        }
        rowmask[i] = m;
    }

    floatx4 acc[4][4];
    #pragma unroll
    for (int rt = 0; rt < 4; rt++)
        #pragma unroll
        for (int nt = 0; nt < 4; nt++)
            acc[rt][nt] = (floatx4){0.f, 0.f, 0.f, 0.f};

    const short* f1s = (const short*)f1b;

    for (int off = 0; off < 27; ++off) {
        const int dz = off / 9, dy = (off / 3) % 3, dx = off % 3;
        const int delta = ((dz - 1) * PLANE + (dy - 1) * DD + (dx - 1)) * 64;

        __syncthreads();

        #pragma unroll
        for (int i = 0; i < 8; i++) {
            int4 v = make_int4(0, 0, 0, 0);
            if ((rowmask[i] >> off) & 1)
                v = *(const int4*)(f1s + rowbase[i] + delta + chunk * 8);
            *(int4*)(&Alds[(r0 + 32 * i) * 72 + chunk * 8]) = v;
        }
        #pragma unroll
        for (int it = 0; it < 2; it++) {
            int idx = it * 256 + tid;
            int oc = idx >> 3, ch = idx & 7;
            int4 v = *(const int4*)(wpb + oc * 1728 + off * 64 + ch * 8);
            *(int4*)(&Blds[oc * 72 + ch * 8]) = v;
        }
        __syncthreads();

        #pragma unroll
        for (int ks = 0; ks < 2; ks++) {
            const int kl = ks * 32 + quad * 8;
            bf16x8 bfr[4];
            #pragma unroll
            for (int nt = 0; nt < 4; nt++)
                bfr[nt] = *(const bf16x8*)(&Blds[(nt * 16 + lc) * 72 + kl]);
            #pragma unroll
            for (int rt = 0; rt < 4; rt++) {
                bf16x8 afr = *(const bf16x8*)(&Alds[(w * 64 + rt * 16 + lc) * 72 + kl]);
                #pragma unroll
                for (int nt = 0; nt < 4; nt++)
                    acc[rt][nt] = __builtin_amdgcn_mfma_f32_16x16x32_bf16(
                        afr, bfr[nt], acc[rt][nt], 0, 0, 0);
            }
        }
    }

    #pragma unroll
    for (int nt = 0; nt < 4; nt++) {
        const int oc = nt * 16 + lc;
        const float bias = b2[oc];
        #pragma unroll
        for (int rt = 0; rt < 4; rt++) {
            const int pt = pbase + w * 64 + rt * 16 + quad * 4;
            #pragma unroll
            for (int r = 0; r < 4; r++) {
                if (pt + r < NPTS) {
                    float v = acc[rt][nt][r] + bias;
                    g[(size_t)(pt + r) * 64 + oc] = __float2bfloat16(v > 0.f ? v : 0.f);
                }
            }
        }
    }
}

// ---------------- K3: fused MLP via MFMA. block = 64 points, 4 waves split N ----------------
// LDS activations bf16 with 16B-chunk XOR swizzle: chunk c of row m -> (c&~7)|((c&7)^(m&7))
__global__ __launch_bounds__(256) void mlp_mfma(
    const __hip_bfloat16* __restrict__ g,
    const short* __restrict__ w1b, const float* __restrict__ bp1,
    const short* __restrict__ w2b, const float* __restrict__ bp2,
    const short* __restrict__ w3b, const float* __restrict__ bp3,
    const float* __restrict__ wp4, const float* __restrict__ bp4,
    float* __restrict__ out)
{
    __shared__ short bufA[64 * 256];   // 32 KB: X (chunks 0-7), then H2
    __shared__ short bufB[64 * 256];   // 32 KB: H1; then fp32 H3 overlay
    float* h3f = (float*)bufB;         // 64 x 65 floats = 16.6 KB

    const int tid = threadIdx.x;
    const int pb = blockIdx.x * 64;
    const int w = tid >> 6, lane = tid & 63;
    const int q = lane >> 4, lc = lane & 15;

    // ---- stage X = g[pb..pb+64) : 64 rows x 64 bf16, swizzled into bufA ----
    const short* gs = (const short*)g;
    #pragma unroll
    for (int it = 0; it < 2; it++) {
        int idx = it * 256 + tid;          // 0..511
        int r = idx >> 3, c = idx & 7;
        int4 v = *(const int4*)(gs + (size_t)(pb + r) * 64 + c * 8);
        *(int4*)(&bufA[r * 256 + (c ^ (r & 7)) * 8]) = v;
    }
    __syncthreads();

    // ---- L1: 64 -> 256, relu. wave n-range = w*64 ----
    {
        floatx4 acc[4][4];
        #pragma unroll
        for (int mt = 0; mt < 4; mt++)
            #pragma unroll
            for (int nt = 0; nt < 4; nt++)
                acc[mt][nt] = (floatx4){0.f, 0.f, 0.f, 0.f};

        #pragma unroll
        for (int ks = 0; ks < 2; ks++) {
            bf16x8 bfr[4];
            #pragma unroll
            for (int nt = 0; nt < 4; nt++)
                bfr[nt] = *(const bf16x8*)(w1b + (w * 64 + nt * 16 + lc) * 64 + ks * 32 + q * 8);
            const int c = ks * 4 + q;
            #pragma unroll
            for (int mt = 0; mt < 4; mt++) {
                const int m = mt * 16 + lc;
                bf16x8 afr = *(const bf16x8*)(&bufA[m * 256 + (c ^ (m & 7)) * 8]);
                #pragma unroll
                for (int nt = 0; nt < 4; nt++)
                    acc[mt][nt] = __builtin_amdgcn_mfma_f32_16x16x32_bf16(afr, bfr[nt], acc[mt][nt], 0, 0, 0);
            }
        }
        float bias[4];
        #pragma unroll
        for (int nt = 0; nt < 4; nt++) bias[nt] = bp1[w * 64 + nt * 16 + lc];
        #pragma unroll
        for (int mt = 0; mt < 4; mt++)
            #pragma unroll
            for (int nt = 0; nt < 4; nt++) {
                const int col = w * 64 + nt * 16 + lc;
                #pragma unroll
                for (int r = 0; r < 4; r++) {
                    const int m = mt * 16 + q * 4 + r;
                    float v = acc[mt][nt][r] + bias[nt];
                    v = v > 0.f ? v : 0.f;
                    bufB[m * 256 + (((col >> 3) ^ (m & 7)) * 8 + (col & 7))] = f2bf(v);
                }
            }
    }
    __syncthreads();

    // ---- L2: 256 -> 256, relu. A = bufB (H1), out -> bufA ----
    {
        floatx4 acc[4][4];
        #pragma unroll
        for (int mt = 0; mt < 4; mt++)
            #pragma unroll
            for (int nt = 0; nt < 4; nt++)
                acc[mt][nt] = (floatx4){0.f, 0.f, 0.f, 0.f};

        #pragma unroll
        for (int ks = 0; ks < 8; ks++) {
            bf16x8 bfr[4];
            #pragma unroll
            for (int nt = 0; nt < 4; nt++)
                bfr[nt] = *(const bf16x8*)(w2b + (w * 64 + nt * 16 + lc) * 256 + ks * 32 + q * 8);
            const int c = ks * 4 + q;
            #pragma unroll
            for (int mt = 0; mt < 4; mt++) {
                const int m = mt * 16 + lc;
                const int pc = (c & 24) | ((c & 7) ^ (m & 7));
                bf16x8 afr = *(const bf16x8*)(&bufB[m * 256 + pc * 8]);
                #pragma unroll
                for (int nt = 0; nt < 4; nt++)
                    acc[mt][nt] = __builtin_amdgcn_mfma_f32_16x16x32_bf16(afr, bfr[nt], acc[mt][nt], 0, 0, 0);
            }
        }
        float bias[4];
        #pragma unroll
        for (int nt = 0; nt < 4; nt++) bias[nt] = bp2[w * 64 + nt * 16 + lc];
        __syncthreads();   // all waves done reading X region of bufA
        #pragma unroll
        for (int mt = 0; mt < 4; mt++)
            #pragma unroll
            for (int nt = 0; nt < 4; nt++) {
                const int col = w * 64 + nt * 16 + lc;
                #pragma unroll
                for (int r = 0; r < 4; r++) {
                    const int m = mt * 16 + q * 4 + r;
                    float v = acc[mt][nt][r] + bias[nt];
                    v = v > 0.f ? v : 0.f;
                    bufA[m * 256 + (((col >> 3) ^ (m & 7)) * 8 + (col & 7))] = f2bf(v);
                }
            }
    }
    __syncthreads();

    // ---- L3: 256 -> 64, no relu. A = bufA (H2), out -> h3f fp32 (overlay bufB) ----
    {
        floatx4 acc[4];
        #pragma unroll
        for (int mt = 0; mt < 4; mt++) acc[mt] = (floatx4){0.f, 0.f, 0.f, 0.f};

        #pragma unroll
        for (int ks = 0; ks < 8; ks++) {
            bf16x8 bfr = *(const bf16x8*)(w3b + (w * 16 + lc) * 256 + ks * 32 + q * 8);
            const int c = ks * 4 + q;
            #pragma unroll
            for (int mt = 0; mt < 4; mt++) {
                const int m = mt * 16 + lc;
                const int pc = (c & 24) | ((c & 7) ^ (m & 7));
                bf16x8 afr = *(const bf16x8*)(&bufA[m * 256 + pc * 8]);
                acc[mt] = __builtin_amdgcn_mfma_f32_16x16x32_bf16(afr, bfr, acc[mt], 0, 0, 0);
            }
        }
        const float bias = bp3[w * 16 + lc];
        const int col = w * 16 + lc;
        __syncthreads();   // all waves done reading bufB (H1)
        #pragma unroll
        for (int mt = 0; mt < 4; mt++)
            #pragma unroll
            for (int r = 0; r < 4; r++) {
                const int m = mt * 16 + q * 4 + r;
                h3f[m * 65 + col] = acc[mt][r] + bias;
            }
    }
    __syncthreads();

    // ---- L4: 64 -> 6, fp32 VALU ----
    for (int e = tid; e < 384; e += 256) {
        int c = e >> 6, p = e & 63;
        float a = bp4[c];
        const float* wr = wp4 + c * 64;
        const float* xr = h3f + p * 65;
        #pragma unroll 8
        for (int k = 0; k < 64; k++) a += wr[k] * xr[k];
        out[(size_t)c * NPTS + pb + p] = a;
    }
}

extern "C" void kernel_launch(void* const* d_in, const int* in_sizes, int n_in,
                              void* d_out, int out_size, void* d_ws, size_t ws_size,
                              hipStream_t stream) {
    const float* img = (const float*)d_in[0];
    const int* c0 = (const int*)d_in[1];
    const int* c1 = (const int*)d_in[2];
    const int* c2 = (const int*)d_in[3];
    const float* w_enc1 = (const float*)d_in[4];
    const float* b_enc1 = (const float*)d_in[5];
    const float* w_enc2 = (const float*)d_in[6];
    const float* b_enc2 = (const float*)d_in[7];
    const float* w_p1 = (const float*)d_in[8];
    const float* b_p1 = (const float*)d_in[9];
    const float* w_p2 = (const float*)d_in[10];
    const float* b_p2 = (const float*)d_in[11];
    const float* w_p3 = (const float*)d_in[12];
    const float* b_p3 = (const float*)d_in[13];
    const float* w_p4 = (const float*)d_in[14];
    const float* b_p4 = (const float*)d_in[15];
    float* out = (float*)d_out;

    short* f1b = (short*)d_ws;                       // 32,768,000 shorts
    short* wpb = f1b + (size_t)VOX * 64;             // 110592
    short* w1b = wpb + 110592;                       // 16384
    short* w2b = w1b + 16384;                        // 65536
    short* w3b = w2b + 65536;                        // 16384
    short* gb  = w3b + 16384;                        // 12,800,000 shorts

    convert_weights<<<(208896 + 255) / 256, 256, 0, stream>>>(
        w_enc2, w_p1, w_p2, w_p3, wpb, w1b, w2b, w3b);
    conv1_kernel<<<DD * DD, 256, 0, stream>>>(img, w_enc1, b_enc1, (__hip_bfloat16*)f1b);
    conv2_mfma<<<(NPTS + 255) / 256, 256, 0, stream>>>(
        (const __hip_bfloat16*)f1b, wpb, b_enc2, c0, c1, c2, (__hip_bfloat16*)gb);
    mlp_mfma<<<NPTS / 64, 256, 0, stream>>>(
        (const __hip_bfloat16*)gb, w1b, b_p1, w2b, b_p2, w3b, b_p3, w_p4, b_p4, out);
}

// Round 4
// 540.974 us; speedup vs baseline: 10.7671x; 3.1656x over previous
//
#include <hip/hip_runtime.h>
#include <hip/hip_bf16.h>

#define DD 80
#define CIN 32
#define PLANE (DD*DD)        // 6400
#define VOX (DD*DD*DD)       // 512000
#define NPTS 200000

typedef __attribute__((ext_vector_type(8))) short bf16x8;
typedef __attribute__((ext_vector_type(4))) float floatx4;

static __device__ __forceinline__ short f2bf(float v) {
    __hip_bfloat16 b = __float2bfloat16(v);
    return *(short*)&b;
}

// ---------------- K0: convert/permute all weights to bf16 ----------------
// wpb[oc][off*64+ic]  from w_enc2(64,64,3,3,3)
// wc1[off][oc][ic]    from w_enc1(64,32,3,3,3)
// w1b/w2b/w3b row-major [n][k] bf16
__global__ void convert_weights(const float* __restrict__ w2,
                                const float* __restrict__ w_p1,
                                const float* __restrict__ w_p2,
                                const float* __restrict__ w_p3,
                                const float* __restrict__ w_e1,
                                short* __restrict__ wpb, short* __restrict__ w1b,
                                short* __restrict__ w2b, short* __restrict__ w3b,
                                short* __restrict__ wc1) {
    int i = blockIdx.x * 256 + threadIdx.x;      // total 264192
    if (i < 110592) {
        int oc = i / 1728, j = i - oc * 1728;
        int off = j >> 6, ic = j & 63;
        wpb[i] = f2bf(w2[oc * 1728 + ic * 27 + off]);
    } else if (i < 110592 + 16384) {
        int j = i - 110592;
        w1b[j] = f2bf(w_p1[j]);
    } else if (i < 110592 + 16384 + 65536) {
        int j = i - 110592 - 16384;
        w2b[j] = f2bf(w_p2[j]);
    } else if (i < 110592 + 16384 + 65536 + 16384) {
        int j = i - 110592 - 16384 - 65536;
        w3b[j] = f2bf(w_p3[j]);
    } else if (i < 110592 + 16384 + 65536 + 16384 + 55296) {
        int j = i - (110592 + 16384 + 65536 + 16384);   // [off][oc][ic]
        int off = j / 2048, r = j - off * 2048;
        int oc = r >> 5, ic = r & 31;
        wc1[j] = f2bf(w_e1[(oc * 32 + ic) * 27 + off]);
    }
}

// ---------------- K0b: transpose img (32,VOX) fp32 -> img_t [vox][32] bf16 ----------------
__global__ __launch_bounds__(256) void transpose_img(
    const float* __restrict__ img, short* __restrict__ img_t)
{
    int v = blockIdx.x * 256 + threadIdx.x;
    if (v >= VOX) return;
    short row[32];
    #pragma unroll
    for (int ic = 0; ic < 32; ic++)
        row[ic] = f2bf(img[(size_t)ic * VOX + v]);
    int4* dst = (int4*)(img_t + (size_t)v * 32);
    #pragma unroll
    for (int c = 0; c < 4; c++) dst[c] = ((int4*)row)[c];
}

// ---------------- K1: conv1 via implicit-GEMM MFMA -> f1 [vox][64] bf16 ----------------
// block = one (d,h) row of 80 voxels. LDS: 9 halo rows x 82 vox x 32 ic, stride 36 shorts.
__global__ __launch_bounds__(256) void conv1_mfma(
    const short* __restrict__ img_t, const short* __restrict__ wc1,
    const float* __restrict__ b1, short* __restrict__ f1)
{
    __shared__ short Alds[738 * 36];   // 53,136 B

    const int bh = blockIdx.x;
    const int d = bh / DD, h = bh - d * DD;
    const int tid = threadIdx.x;
    const int w = tid >> 6, lane = tid & 63;
    const int q = lane >> 4, lc = lane & 15;

    // stage halo: 738 rows x 64 B (4 int4 chunks each) = 2952 int4
    for (int i = 0; i < 12; i++) {
        int idx = i * 256 + tid;
        if (idx < 2952) {
            int row = idx >> 2, c = idx & 3;
            int rr = row / 82, v = row - rr * 82;
            int dz = rr / 3, dy = rr - dz * 3;
            int zz = d + dz - 1, yy = h + dy - 1, ww = v - 1;
            int4 val = make_int4(0, 0, 0, 0);
            if ((unsigned)zz < DD && (unsigned)yy < DD && (unsigned)ww < DD)
                val = *(const int4*)(img_t + ((size_t)(zz * PLANE + yy * DD + ww)) * 32 + c * 8);
            *(int4*)(&Alds[row * 36 + c * 8]) = val;
        }
    }
    __syncthreads();

    floatx4 acc[5];
    #pragma unroll
    for (int mt = 0; mt < 5; mt++) acc[mt] = (floatx4){0.f, 0.f, 0.f, 0.f};

    #pragma unroll 3
    for (int off = 0; off < 27; ++off) {
        const int dz = off / 9, rem = off - dz * 9;
        const int dy = rem / 3, dx = rem - dy * 3;
        const int rr = dz * 3 + dy;
        // B-frag: oc = w*16+lc, k-chunk q*8 (wc1 [off][oc][ic], ic contiguous)
        bf16x8 bfr = *(const bf16x8*)(wc1 + ((off * 64 + w * 16 + lc) << 5) + q * 8);
        #pragma unroll
        for (int mt = 0; mt < 5; mt++) {
            const int vv = rr * 82 + mt * 16 + lc + dx;
            bf16x8 afr = *(const bf16x8*)(&Alds[vv * 36 + q * 8]);
            acc[mt] = __builtin_amdgcn_mfma_f32_16x16x32_bf16(afr, bfr, acc[mt], 0, 0, 0);
        }
    }

    const int oc = w * 16 + lc;
    const float bias = b1[oc];
    const size_t vbase = (size_t)(d * DD + h) * DD;
    #pragma unroll
    for (int mt = 0; mt < 5; mt++) {
        #pragma unroll
        for (int r = 0; r < 4; r++) {
            const int m = mt * 16 + q * 4 + r;   // voxel in row
            float v = acc[mt][r] + bias;
            f1[(vbase + m) * 64 + oc] = f2bf(v > 0.f ? v : 0.f);
        }
    }
}

// ---------------- K2: conv2 at gathered points via bf16 MFMA -> g [pt][64] bf16 ----------------
__global__ __launch_bounds__(256) void conv2_mfma(
    const __hip_bfloat16* __restrict__ f1b, const short* __restrict__ wpb,
    const float* __restrict__ b2,
    const int* __restrict__ c0, const int* __restrict__ c1, const int* __restrict__ c2,
    __hip_bfloat16* __restrict__ g)
{
    __shared__ short Alds[256 * 72];   // 36 KB, padded stride 72
    __shared__ short Blds[64 * 72];    // 9 KB

    const int tid = threadIdx.x;
    const int pbase = blockIdx.x * 256;
    const int w = tid >> 6, lane = tid & 63;
    const int quad = lane >> 4, lc = lane & 15;

    const int r0 = tid >> 3, chunk = tid & 7;
    int rowbase[8];
    int rowmask[8];
    #pragma unroll
    for (int i = 0; i < 8; i++) {
        int r = r0 + 32 * i;
        int p = pbase + r; if (p > NPTS - 1) p = NPTS - 1;
        int z = c0[p], y = c1[p], x = c2[p];
        rowbase[i] = (z * PLANE + y * DD + x) * 64;
        int m = 0;
        #pragma unroll
        for (int off = 0; off < 27; off++) {
            int dz = off / 9, dy = (off / 3) % 3, dx = off % 3;
            int ok = ((unsigned)(z + dz - 1) < DD) & ((unsigned)(y + dy - 1) < DD) &
                     ((unsigned)(x + dx - 1) < DD);
            m |= ok << off;
        }
        rowmask[i] = m;
    }

    floatx4 acc[4][4];
    #pragma unroll
    for (int rt = 0; rt < 4; rt++)
        #pragma unroll
        for (int nt = 0; nt < 4; nt++)
            acc[rt][nt] = (floatx4){0.f, 0.f, 0.f, 0.f};

    const short* f1s = (const short*)f1b;

    for (int off = 0; off < 27; ++off) {
        const int dz = off / 9, dy = (off / 3) % 3, dx = off % 3;
        const int delta = ((dz - 1) * PLANE + (dy - 1) * DD + (dx - 1)) * 64;

        __syncthreads();

        #pragma unroll
        for (int i = 0; i < 8; i++) {
            int4 v = make_int4(0, 0, 0, 0);
            if ((rowmask[i] >> off) & 1)
                v = *(const int4*)(f1s + rowbase[i] + delta + chunk * 8);
            *(int4*)(&Alds[(r0 + 32 * i) * 72 + chunk * 8]) = v;
        }
        #pragma unroll
        for (int it = 0; it < 2; it++) {
            int idx = it * 256 + tid;
            int oc = idx >> 3, ch = idx & 7;
            int4 v = *(const int4*)(wpb + oc * 1728 + off * 64 + ch * 8);
            *(int4*)(&Blds[oc * 72 + ch * 8]) = v;
        }
        __syncthreads();

        #pragma unroll
        for (int ks = 0; ks < 2; ks++) {
            const int kl = ks * 32 + quad * 8;
            bf16x8 bfr[4];
            #pragma unroll
            for (int nt = 0; nt < 4; nt++)
                bfr[nt] = *(const bf16x8*)(&Blds[(nt * 16 + lc) * 72 + kl]);
            #pragma unroll
            for (int rt = 0; rt < 4; rt++) {
                bf16x8 afr = *(const bf16x8*)(&Alds[(w * 64 + rt * 16 + lc) * 72 + kl]);
                #pragma unroll
                for (int nt = 0; nt < 4; nt++)
                    acc[rt][nt] = __builtin_amdgcn_mfma_f32_16x16x32_bf16(
                        afr, bfr[nt], acc[rt][nt], 0, 0, 0);
            }
        }
    }

    #pragma unroll
    for (int nt = 0; nt < 4; nt++) {
        const int oc = nt * 16 + lc;
        const float bias = b2[oc];
        #pragma unroll
        for (int rt = 0; rt < 4; rt++) {
            const int pt = pbase + w * 64 + rt * 16 + quad * 4;
            #pragma unroll
            for (int r = 0; r < 4; r++) {
                if (pt + r < NPTS) {
                    float v = acc[rt][nt][r] + bias;
                    g[(size_t)(pt + r) * 64 + oc] = __float2bfloat16(v > 0.f ? v : 0.f);
                }
            }
        }
    }
}

// ---------------- K3: fused MLP via MFMA. block = 64 points, 4 waves split N ----------------
__global__ __launch_bounds__(256) void mlp_mfma(
    const __hip_bfloat16* __restrict__ g,
    const short* __restrict__ w1b, const float* __restrict__ bp1,
    const short* __restrict__ w2b, const float* __restrict__ bp2,
    const short* __restrict__ w3b, const float* __restrict__ bp3,
    const float* __restrict__ wp4, const float* __restrict__ bp4,
    float* __restrict__ out)
{
    __shared__ short bufA[64 * 256];   // 32 KB: X (chunks 0-7), then H2
    __shared__ short bufB[64 * 256];   // 32 KB: H1; then fp32 H3 overlay
    float* h3f = (float*)bufB;

    const int tid = threadIdx.x;
    const int pb = blockIdx.x * 64;
    const int w = tid >> 6, lane = tid & 63;
    const int q = lane >> 4, lc = lane & 15;

    const short* gs = (const short*)g;
    #pragma unroll
    for (int it = 0; it < 2; it++) {
        int idx = it * 256 + tid;
        int r = idx >> 3, c = idx & 7;
        int4 v = *(const int4*)(gs + (size_t)(pb + r) * 64 + c * 8);
        *(int4*)(&bufA[r * 256 + (c ^ (r & 7)) * 8]) = v;
    }
    __syncthreads();

    // L1: 64 -> 256, relu
    {
        floatx4 acc[4][4];
        #pragma unroll
        for (int mt = 0; mt < 4; mt++)
            #pragma unroll
            for (int nt = 0; nt < 4; nt++)
                acc[mt][nt] = (floatx4){0.f, 0.f, 0.f, 0.f};

        #pragma unroll
        for (int ks = 0; ks < 2; ks++) {
            bf16x8 bfr[4];
            #pragma unroll
            for (int nt = 0; nt < 4; nt++)
                bfr[nt] = *(const bf16x8*)(w1b + (w * 64 + nt * 16 + lc) * 64 + ks * 32 + q * 8);
            const int c = ks * 4 + q;
            #pragma unroll
            for (int mt = 0; mt < 4; mt++) {
                const int m = mt * 16 + lc;
                bf16x8 afr = *(const bf16x8*)(&bufA[m * 256 + (c ^ (m & 7)) * 8]);
                #pragma unroll
                for (int nt = 0; nt < 4; nt++)
                    acc[mt][nt] = __builtin_amdgcn_mfma_f32_16x16x32_bf16(afr, bfr[nt], acc[mt][nt], 0, 0, 0);
            }
        }
        float bias[4];
        #pragma unroll
        for (int nt = 0; nt < 4; nt++) bias[nt] = bp1[w * 64 + nt * 16 + lc];
        #pragma unroll
        for (int mt = 0; mt < 4; mt++)
            #pragma unroll
            for (int nt = 0; nt < 4; nt++) {
                const int col = w * 64 + nt * 16 + lc;
                #pragma unroll
                for (int r = 0; r < 4; r++) {
                    const int m = mt * 16 + q * 4 + r;
                    float v = acc[mt][nt][r] + bias[nt];
                    v = v > 0.f ? v : 0.f;
                    bufB[m * 256 + (((col >> 3) ^ (m & 7)) * 8 + (col & 7))] = f2bf(v);
                }
            }
    }
    __syncthreads();

    // L2: 256 -> 256, relu
    {
        floatx4 acc[4][4];
        #pragma unroll
        for (int mt = 0; mt < 4; mt++)
            #pragma unroll
            for (int nt = 0; nt < 4; nt++)
                acc[mt][nt] = (floatx4){0.f, 0.f, 0.f, 0.f};

        #pragma unroll
        for (int ks = 0; ks < 8; ks++) {
            bf16x8 bfr[4];
            #pragma unroll
            for (int nt = 0; nt < 4; nt++)
                bfr[nt] = *(const bf16x8*)(w2b + (w * 64 + nt * 16 + lc) * 256 + ks * 32 + q * 8);
            const int c = ks * 4 + q;
            #pragma unroll
            for (int mt = 0; mt < 4; mt++) {
                const int m = mt * 16 + lc;
                const int pc = (c & 24) | ((c & 7) ^ (m & 7));
                bf16x8 afr = *(const bf16x8*)(&bufB[m * 256 + pc * 8]);
                #pragma unroll
                for (int nt = 0; nt < 4; nt++)
                    acc[mt][nt] = __builtin_amdgcn_mfma_f32_16x16x32_bf16(afr, bfr[nt], acc[mt][nt], 0, 0, 0);
            }
        }
        float bias[4];
        #pragma unroll
        for (int nt = 0; nt < 4; nt++) bias[nt] = bp2[w * 64 + nt * 16 + lc];
        __syncthreads();
        #pragma unroll
        for (int mt = 0; mt < 4; mt++)
            #pragma unroll
            for (int nt = 0; nt < 4; nt++) {
                const int col = w * 64 + nt * 16 + lc;
                #pragma unroll
                for (int r = 0; r < 4; r++) {
                    const int m = mt * 16 + q * 4 + r;
                    float v = acc[mt][nt][r] + bias[nt];
                    v = v > 0.f ? v : 0.f;
                    bufA[m * 256 + (((col >> 3) ^ (m & 7)) * 8 + (col & 7))] = f2bf(v);
                }
            }
    }
    __syncthreads();

    // L3: 256 -> 64
    {
        floatx4 acc[4];
        #pragma unroll
        for (int mt = 0; mt < 4; mt++) acc[mt] = (floatx4){0.f, 0.f, 0.f, 0.f};

        #pragma unroll
        for (int ks = 0; ks < 8; ks++) {
            bf16x8 bfr = *(const bf16x8*)(w3b + (w * 16 + lc) * 256 + ks * 32 + q * 8);
            const int c = ks * 4 + q;
            #pragma unroll
            for (int mt = 0; mt < 4; mt++) {
                const int m = mt * 16 + lc;
                const int pc = (c & 24) | ((c & 7) ^ (m & 7));
                bf16x8 afr = *(const bf16x8*)(&bufA[m * 256 + pc * 8]);
                acc[mt] = __builtin_amdgcn_mfma_f32_16x16x32_bf16(afr, bfr, acc[mt], 0, 0, 0);
            }
        }
        const float bias = bp3[w * 16 + lc];
        const int col = w * 16 + lc;
        __syncthreads();
        #pragma unroll
        for (int mt = 0; mt < 4; mt++)
            #pragma unroll
            for (int r = 0; r < 4; r++) {
                const int m = mt * 16 + q * 4 + r;
                h3f[m * 65 + col] = acc[mt][r] + bias;
            }
    }
    __syncthreads();

    // L4: 64 -> 6
    for (int e = tid; e < 384; e += 256) {
        int c = e >> 6, p = e & 63;
        float a = bp4[c];
        const float* wr = wp4 + c * 64;
        const float* xr = h3f + p * 65;
        #pragma unroll 8
        for (int k = 0; k < 64; k++) a += wr[k] * xr[k];
        out[(size_t)c * NPTS + pb + p] = a;
    }
}

extern "C" void kernel_launch(void* const* d_in, const int* in_sizes, int n_in,
                              void* d_out, int out_size, void* d_ws, size_t ws_size,
                              hipStream_t stream) {
    const float* img = (const float*)d_in[0];
    const int* c0 = (const int*)d_in[1];
    const int* c1 = (const int*)d_in[2];
    const int* c2 = (const int*)d_in[3];
    const float* w_enc1 = (const float*)d_in[4];
    const float* b_enc1 = (const float*)d_in[5];
    const float* w_enc2 = (const float*)d_in[6];
    const float* b_enc2 = (const float*)d_in[7];
    const float* w_p1 = (const float*)d_in[8];
    const float* b_p1 = (const float*)d_in[9];
    const float* w_p2 = (const float*)d_in[10];
    const float* b_p2 = (const float*)d_in[11];
    const float* w_p3 = (const float*)d_in[12];
    const float* b_p3 = (const float*)d_in[13];
    const float* w_p4 = (const float*)d_in[14];
    const float* b_p4 = (const float*)d_in[15];
    float* out = (float*)d_out;

    short* f1b = (short*)d_ws;                       // 32,768,000
    short* wpb = f1b + (size_t)VOX * 64;             // 110592
    short* w1b = wpb + 110592;                       // 16384
    short* w2b = w1b + 16384;                        // 65536
    short* w3b = w2b + 65536;                        // 16384
    short* gb  = w3b + 16384;                        // 12,800,000
    short* img_t = gb + (size_t)NPTS * 64;           // 16,384,000
    short* wc1 = img_t + (size_t)VOX * 32;           // 55296

    convert_weights<<<(264192 + 255) / 256, 256, 0, stream>>>(
        w_enc2, w_p1, w_p2, w_p3, w_enc1, wpb, w1b, w2b, w3b, wc1);
    transpose_img<<<(VOX + 255) / 256, 256, 0, stream>>>(img, img_t);
    conv1_mfma<<<DD * DD, 256, 0, stream>>>(img_t, wc1, b_enc1, f1b);
    conv2_mfma<<<(NPTS + 255) / 256, 256, 0, stream>>>(
        (const __hip_bfloat16*)f1b, wpb, b_enc2, c0, c1, c2, (__hip_bfloat16*)gb);
    mlp_mfma<<<NPTS / 64, 256, 0, stream>>>(
        (const __hip_bfloat16*)gb, w1b, b_p1, w2b, b_p2, w3b, b_p3, w_p4, b_p4, out);
}

// Round 5
// 536.626 us; speedup vs baseline: 10.8543x; 1.0081x over previous
//
#include <hip/hip_runtime.h>
#include <hip/hip_bf16.h>

#define DD 80
#define CIN 32
#define PLANE (DD*DD)        // 6400
#define VOX (DD*DD*DD)       // 512000
#define NPTS 200000

typedef __attribute__((ext_vector_type(8))) short bf16x8;
typedef __attribute__((ext_vector_type(4))) float floatx4;

static __device__ __forceinline__ short f2bf(float v) {
    __hip_bfloat16 b = __float2bfloat16(v);
    return *(short*)&b;
}

// ---------------- K0: convert/permute all weights to bf16 ----------------
__global__ void convert_weights(const float* __restrict__ w2,
                                const float* __restrict__ w_p1,
                                const float* __restrict__ w_p2,
                                const float* __restrict__ w_p3,
                                const float* __restrict__ w_e1,
                                short* __restrict__ wpb, short* __restrict__ w1b,
                                short* __restrict__ w2b, short* __restrict__ w3b,
                                short* __restrict__ wc1) {
    int i = blockIdx.x * 256 + threadIdx.x;      // total 264192
    if (i < 110592) {
        int oc = i / 1728, j = i - oc * 1728;
        int off = j >> 6, ic = j & 63;
        wpb[i] = f2bf(w2[oc * 1728 + ic * 27 + off]);
    } else if (i < 110592 + 16384) {
        int j = i - 110592;
        w1b[j] = f2bf(w_p1[j]);
    } else if (i < 110592 + 16384 + 65536) {
        int j = i - 110592 - 16384;
        w2b[j] = f2bf(w_p2[j]);
    } else if (i < 110592 + 16384 + 65536 + 16384) {
        int j = i - 110592 - 16384 - 65536;
        w3b[j] = f2bf(w_p3[j]);
    } else if (i < 110592 + 16384 + 65536 + 16384 + 55296) {
        int j = i - (110592 + 16384 + 65536 + 16384);   // [off][oc][ic]
        int off = j / 2048, r = j - off * 2048;
        int oc = r >> 5, ic = r & 31;
        wc1[j] = f2bf(w_e1[(oc * 32 + ic) * 27 + off]);
    }
}

// ---------------- K0b: transpose img (32,VOX) fp32 -> img_t [vox][32] bf16 ----------------
__global__ __launch_bounds__(256) void transpose_img(
    const float* __restrict__ img, short* __restrict__ img_t)
{
    int v = blockIdx.x * 256 + threadIdx.x;
    if (v >= VOX) return;
    short row[32];
    #pragma unroll
    for (int ic = 0; ic < 32; ic++)
        row[ic] = f2bf(img[(size_t)ic * VOX + v]);
    int4* dst = (int4*)(img_t + (size_t)v * 32);
    #pragma unroll
    for (int c = 0; c < 4; c++) dst[c] = ((int4*)row)[c];
}

// ---------------- K1: conv1 via implicit-GEMM MFMA -> f1 [vox][64] bf16 ----------------
__global__ __launch_bounds__(256) void conv1_mfma(
    const short* __restrict__ img_t, const short* __restrict__ wc1,
    const float* __restrict__ b1, short* __restrict__ f1)
{
    __shared__ short Alds[738 * 36];   // 53,136 B

    const int bh = blockIdx.x;
    const int d = bh / DD, h = bh - d * DD;
    const int tid = threadIdx.x;
    const int w = tid >> 6, lane = tid & 63;
    const int q = lane >> 4, lc = lane & 15;

    for (int i = 0; i < 12; i++) {
        int idx = i * 256 + tid;
        if (idx < 2952) {
            int row = idx >> 2, c = idx & 3;
            int rr = row / 82, v = row - rr * 82;
            int dz = rr / 3, dy = rr - dz * 3;
            int zz = d + dz - 1, yy = h + dy - 1, ww = v - 1;
            int4 val = make_int4(0, 0, 0, 0);
            if ((unsigned)zz < DD && (unsigned)yy < DD && (unsigned)ww < DD)
                val = *(const int4*)(img_t + ((size_t)(zz * PLANE + yy * DD + ww)) * 32 + c * 8);
            *(int4*)(&Alds[row * 36 + c * 8]) = val;
        }
    }
    __syncthreads();

    floatx4 acc[5];
    #pragma unroll
    for (int mt = 0; mt < 5; mt++) acc[mt] = (floatx4){0.f, 0.f, 0.f, 0.f};

    #pragma unroll 3
    for (int off = 0; off < 27; ++off) {
        const int dz = off / 9, rem = off - dz * 9;
        const int dy = rem / 3, dx = rem - dy * 3;
        const int rr = dz * 3 + dy;
        bf16x8 bfr = *(const bf16x8*)(wc1 + ((off * 64 + w * 16 + lc) << 5) + q * 8);
        #pragma unroll
        for (int mt = 0; mt < 5; mt++) {
            const int vv = rr * 82 + mt * 16 + lc + dx;
            bf16x8 afr = *(const bf16x8*)(&Alds[vv * 36 + q * 8]);
            acc[mt] = __builtin_amdgcn_mfma_f32_16x16x32_bf16(afr, bfr, acc[mt], 0, 0, 0);
        }
    }

    const int oc = w * 16 + lc;
    const float bias = b1[oc];
    const size_t vbase = (size_t)(d * DD + h) * DD;
    #pragma unroll
    for (int mt = 0; mt < 5; mt++) {
        #pragma unroll
        for (int r = 0; r < 4; r++) {
            const int m = mt * 16 + q * 4 + r;
            float v = acc[mt][r] + bias;
            f1[(vbase + m) * 64 + oc] = f2bf(v > 0.f ? v : 0.f);
        }
    }
}

// ---------------- K2: conv2 at gathered points, barrier-free direct-gather MFMA ----------------
// wave = 64 points x 64 oc. A-frags gathered straight from global (no LDS, no syncthreads).
__global__ __launch_bounds__(256) void conv2_mfma(
    const short* __restrict__ f1s, const short* __restrict__ wpb,
    const float* __restrict__ b2,
    const int* __restrict__ c0, const int* __restrict__ c1, const int* __restrict__ c2,
    __hip_bfloat16* __restrict__ g)
{
    const int tid = threadIdx.x;
    const int w = tid >> 6, lane = tid & 63;
    const int q = lane >> 4, lc = lane & 15;
    const int pw = blockIdx.x * 256 + w * 64;    // wave's point base

    // per-lane: 4 points (m = mt*16 + lc)
    int rowbase[4];
    int rowmask[4];
    #pragma unroll
    for (int mt = 0; mt < 4; mt++) {
        int p = pw + mt * 16 + lc;
        if (p > NPTS - 1) p = NPTS - 1;
        int z = c0[p], y = c1[p], x = c2[p];
        rowbase[mt] = (z * PLANE + y * DD + x) * 64;
        int m = 0;
        #pragma unroll
        for (int off = 0; off < 27; off++) {
            int dz = off / 9, dy = (off / 3) % 3, dx = off % 3;
            int ok = ((unsigned)(z + dz - 1) < DD) & ((unsigned)(y + dy - 1) < DD) &
                     ((unsigned)(x + dx - 1) < DD);
            m |= ok << off;
        }
        rowmask[mt] = m;
    }

    floatx4 acc[4][4];
    #pragma unroll
    for (int mt = 0; mt < 4; mt++)
        #pragma unroll
        for (int nt = 0; nt < 4; nt++)
            acc[mt][nt] = (floatx4){0.f, 0.f, 0.f, 0.f};

    #pragma unroll 3
    for (int off = 0; off < 27; ++off) {
        const int dz = off / 9, rem = off - dz * 9;
        const int dy = rem / 3, dx = rem - dy * 3;
        const int delta = ((dz - 1) * PLANE + (dy - 1) * DD + (dx - 1)) * 64;

        // A-frags: 4 mt x 2 ks masked direct gathers (16 B each)
        bf16x8 afr[4][2];
        #pragma unroll
        for (int mt = 0; mt < 4; mt++) {
            const int valid = (rowmask[mt] >> off) & 1;
            #pragma unroll
            for (int ks = 0; ks < 2; ks++) {
                bf16x8 v = (bf16x8)(short)0;
                if (valid)
                    v = *(const bf16x8*)(f1s + rowbase[mt] + delta + ks * 32 + q * 8);
                afr[mt][ks] = v;
            }
        }
        // B-frags: 4 nt x 2 ks from global (L2-resident, 216 KB total)
        bf16x8 bfr[4][2];
        #pragma unroll
        for (int nt = 0; nt < 4; nt++)
            #pragma unroll
            for (int ks = 0; ks < 2; ks++)
                bfr[nt][ks] = *(const bf16x8*)(wpb + (nt * 16 + lc) * 1728 + off * 64 + ks * 32 + q * 8);

        #pragma unroll
        for (int ks = 0; ks < 2; ks++)
            #pragma unroll
            for (int mt = 0; mt < 4; mt++)
                #pragma unroll
                for (int nt = 0; nt < 4; nt++)
                    acc[mt][nt] = __builtin_amdgcn_mfma_f32_16x16x32_bf16(
                        afr[mt][ks], bfr[nt][ks], acc[mt][nt], 0, 0, 0);
    }

    #pragma unroll
    for (int nt = 0; nt < 4; nt++) {
        const int oc = nt * 16 + lc;
        const float bias = b2[oc];
        #pragma unroll
        for (int mt = 0; mt < 4; mt++) {
            const int pt = pw + mt * 16 + q * 4;
            #pragma unroll
            for (int r = 0; r < 4; r++) {
                if (pt + r < NPTS) {
                    float v = acc[mt][nt][r] + bias;
                    g[(size_t)(pt + r) * 64 + oc] = __float2bfloat16(v > 0.f ? v : 0.f);
                }
            }
        }
    }
}

// ---------------- K3: fused MLP via MFMA. block = 64 points, 4 waves split N ----------------
__global__ __launch_bounds__(256) void mlp_mfma(
    const __hip_bfloat16* __restrict__ g,
    const short* __restrict__ w1b, const float* __restrict__ bp1,
    const short* __restrict__ w2b, const float* __restrict__ bp2,
    const short* __restrict__ w3b, const float* __restrict__ bp3,
    const float* __restrict__ wp4, const float* __restrict__ bp4,
    float* __restrict__ out)
{
    __shared__ short bufA[64 * 256];   // 32 KB: X, then H2
    __shared__ short bufB[64 * 256];   // 32 KB: H1; then fp32 H3 overlay
    float* h3f = (float*)bufB;

    const int tid = threadIdx.x;
    const int pb = blockIdx.x * 64;
    const int w = tid >> 6, lane = tid & 63;
    const int q = lane >> 4, lc = lane & 15;

    const short* gs = (const short*)g;
    #pragma unroll
    for (int it = 0; it < 2; it++) {
        int idx = it * 256 + tid;
        int r = idx >> 3, c = idx & 7;
        int4 v = *(const int4*)(gs + (size_t)(pb + r) * 64 + c * 8);
        *(int4*)(&bufA[r * 256 + (c ^ (r & 7)) * 8]) = v;
    }
    __syncthreads();

    // L1: 64 -> 256, relu
    {
        floatx4 acc[4][4];
        #pragma unroll
        for (int mt = 0; mt < 4; mt++)
            #pragma unroll
            for (int nt = 0; nt < 4; nt++)
                acc[mt][nt] = (floatx4){0.f, 0.f, 0.f, 0.f};

        #pragma unroll
        for (int ks = 0; ks < 2; ks++) {
            bf16x8 bfr[4];
            #pragma unroll
            for (int nt = 0; nt < 4; nt++)
                bfr[nt] = *(const bf16x8*)(w1b + (w * 64 + nt * 16 + lc) * 64 + ks * 32 + q * 8);
            const int c = ks * 4 + q;
            #pragma unroll
            for (int mt = 0; mt < 4; mt++) {
                const int m = mt * 16 + lc;
                bf16x8 afr = *(const bf16x8*)(&bufA[m * 256 + (c ^ (m & 7)) * 8]);
                #pragma unroll
                for (int nt = 0; nt < 4; nt++)
                    acc[mt][nt] = __builtin_amdgcn_mfma_f32_16x16x32_bf16(afr, bfr[nt], acc[mt][nt], 0, 0, 0);
            }
        }
        float bias[4];
        #pragma unroll
        for (int nt = 0; nt < 4; nt++) bias[nt] = bp1[w * 64 + nt * 16 + lc];
        #pragma unroll
        for (int mt = 0; mt < 4; mt++)
            #pragma unroll
            for (int nt = 0; nt < 4; nt++) {
                const int col = w * 64 + nt * 16 + lc;
                #pragma unroll
                for (int r = 0; r < 4; r++) {
                    const int m = mt * 16 + q * 4 + r;
                    float v = acc[mt][nt][r] + bias[nt];
                    v = v > 0.f ? v : 0.f;
                    bufB[m * 256 + (((col >> 3) ^ (m & 7)) * 8 + (col & 7))] = f2bf(v);
                }
            }
    }
    __syncthreads();

    // L2: 256 -> 256, relu
    {
        floatx4 acc[4][4];
        #pragma unroll
        for (int mt = 0; mt < 4; mt++)
            #pragma unroll
            for (int nt = 0; nt < 4; nt++)
                acc[mt][nt] = (floatx4){0.f, 0.f, 0.f, 0.f};

        #pragma unroll
        for (int ks = 0; ks < 8; ks++) {
            bf16x8 bfr[4];
            #pragma unroll
            for (int nt = 0; nt < 4; nt++)
                bfr[nt] = *(const bf16x8*)(w2b + (w * 64 + nt * 16 + lc) * 256 + ks * 32 + q * 8);
            const int c = ks * 4 + q;
            #pragma unroll
            for (int mt = 0; mt < 4; mt++) {
                const int m = mt * 16 + lc;
                const int pc = (c & 24) | ((c & 7) ^ (m & 7));
                bf16x8 afr = *(const bf16x8*)(&bufB[m * 256 + pc * 8]);
                #pragma unroll
                for (int nt = 0; nt < 4; nt++)
                    acc[mt][nt] = __builtin_amdgcn_mfma_f32_16x16x32_bf16(afr, bfr[nt], acc[mt][nt], 0, 0, 0);
            }
        }
        float bias[4];
        #pragma unroll
        for (int nt = 0; nt < 4; nt++) bias[nt] = bp2[w * 64 + nt * 16 + lc];
        __syncthreads();
        #pragma unroll
        for (int mt = 0; mt < 4; mt++)
            #pragma unroll
            for (int nt = 0; nt < 4; nt++) {
                const int col = w * 64 + nt * 16 + lc;
                #pragma unroll
                for (int r = 0; r < 4; r++) {
                    const int m = mt * 16 + q * 4 + r;
                    float v = acc[mt][nt][r] + bias[nt];
                    v = v > 0.f ? v : 0.f;
                    bufA[m * 256 + (((col >> 3) ^ (m & 7)) * 8 + (col & 7))] = f2bf(v);
                }
            }
    }
    __syncthreads();

    // L3: 256 -> 64
    {
        floatx4 acc[4];
        #pragma unroll
        for (int mt = 0; mt < 4; mt++) acc[mt] = (floatx4){0.f, 0.f, 0.f, 0.f};

        #pragma unroll
        for (int ks = 0; ks < 8; ks++) {
            bf16x8 bfr = *(const bf16x8*)(w3b + (w * 16 + lc) * 256 + ks * 32 + q * 8);
            const int c = ks * 4 + q;
            #pragma unroll
            for (int mt = 0; mt < 4; mt++) {
                const int m = mt * 16 + lc;
                const int pc = (c & 24) | ((c & 7) ^ (m & 7));
                bf16x8 afr = *(const bf16x8*)(&bufA[m * 256 + pc * 8]);
                acc[mt] = __builtin_amdgcn_mfma_f32_16x16x32_bf16(afr, bfr, acc[mt], 0, 0, 0);
            }
        }
        const float bias = bp3[w * 16 + lc];
        const int col = w * 16 + lc;
        __syncthreads();
        #pragma unroll
        for (int mt = 0; mt < 4; mt++)
            #pragma unroll
            for (int r = 0; r < 4; r++) {
                const int m = mt * 16 + q * 4 + r;
                h3f[m * 65 + col] = acc[mt][r] + bias;
            }
    }
    __syncthreads();

    // L4: 64 -> 6
    for (int e = tid; e < 384; e += 256) {
        int c = e >> 6, p = e & 63;
        float a = bp4[c];
        const float* wr = wp4 + c * 64;
        const float* xr = h3f + p * 65;
        #pragma unroll 8
        for (int k = 0; k < 64; k++) a += wr[k] * xr[k];
        out[(size_t)c * NPTS + pb + p] = a;
    }
}

extern "C" void kernel_launch(void* const* d_in, const int* in_sizes, int n_in,
                              void* d_out, int out_size, void* d_ws, size_t ws_size,
                              hipStream_t stream) {
    const float* img = (const float*)d_in[0];
    const int* c0 = (const int*)d_in[1];
    const int* c1 = (const int*)d_in[2];
    const int* c2 = (const int*)d_in[3];
    const float* w_enc1 = (const float*)d_in[4];
    const float* b_enc1 = (const float*)d_in[5];
    const float* w_enc2 = (const float*)d_in[6];
    const float* b_enc2 = (const float*)d_in[7];
    const float* w_p1 = (const float*)d_in[8];
    const float* b_p1 = (const float*)d_in[9];
    const float* w_p2 = (const float*)d_in[10];
    const float* b_p2 = (const float*)d_in[11];
    const float* w_p3 = (const float*)d_in[12];
    const float* b_p3 = (const float*)d_in[13];
    const float* w_p4 = (const float*)d_in[14];
    const float* b_p4 = (const float*)d_in[15];
    float* out = (float*)d_out;

    short* f1b = (short*)d_ws;                       // 32,768,000
    short* wpb = f1b + (size_t)VOX * 64;             // 110592
    short* w1b = wpb + 110592;                       // 16384
    short* w2b = w1b + 16384;                        // 65536
    short* w3b = w2b + 65536;                        // 16384
    short* gb  = w3b + 16384;                        // 12,800,000
    short* img_t = gb + (size_t)NPTS * 64;           // 16,384,000
    short* wc1 = img_t + (size_t)VOX * 32;           // 55296

    convert_weights<<<(264192 + 255) / 256, 256, 0, stream>>>(
        w_enc2, w_p1, w_p2, w_p3, w_enc1, wpb, w1b, w2b, w3b, wc1);
    transpose_img<<<(VOX + 255) / 256, 256, 0, stream>>>(img, img_t);
    conv1_mfma<<<DD * DD, 256, 0, stream>>>(img_t, wc1, b_enc1, f1b);
    conv2_mfma<<<(NPTS + 255) / 256, 256, 0, stream>>>(
        f1b, wpb, b_enc2, c0, c1, c2, (__hip_bfloat16*)gb);
    mlp_mfma<<<NPTS / 64, 256, 0, stream>>>(
        (const __hip_bfloat16*)gb, w1b, b_p1, w2b, b_p2, w3b, b_p3, w_p4, b_p4, out);
}